// Round 18
// baseline (163.603 us; speedup 1.0000x reference)
//
#include <hip/hip_runtime.h>
#include <hip/hip_bf16.h>
#include <math.h>

// Problem constants
#define NB 96        // batch / nodes
#define TT 160       // sequence length
#define DD 96        // feature dim
#define D_STATE 64
#define D_CONV 4
#define HEADDIM 32
#define NGROUPS 6
#define D_INNER 192
#define NHEADS 6
#define EMB 24
#define DOUT 64
#define D_IN_PROJ 1158
#define ZXW_LD 1160  // bf16 zxbcdt row stride (shorts), cols 1158/1159 = pad
#define CONV_DIM 960
#define TN 15360     // TT*DD = input row stride per node, also rows of z
#define BN_EPS 1e-5f
#define RMS_EPS 1e-5f

typedef __attribute__((ext_vector_type(8))) short short8;
typedef __attribute__((ext_vector_type(4))) float f32x4;

__device__ __forceinline__ float siluf(float x) { return x / (1.f + expf(-x)); }
__device__ __forceinline__ float softplusf(float x) {
    return fmaxf(x, 0.f) + log1pf(expf(-fabsf(x)));
}
__device__ __forceinline__ unsigned short bf16r(float x) {
  union { __hip_bfloat16 h; unsigned short u; } cv;
  cv.h = __float2bfloat16(x);
  return cv.u;
}
__device__ __forceinline__ unsigned int pack_bf2(float a, float b) {
  return (unsigned int)bf16r(a) | ((unsigned int)bf16r(b) << 16);
}
__device__ __forceinline__ float bf16f(unsigned short u) {
  return __uint_as_float((unsigned int)u << 16);
}

// ---------------------------------------------------------------------------
// K1: per-t aggregation: a-embeddings, s1, s2, gin = xs + agg
// ---------------------------------------------------------------------------
__global__ __launch_bounds__(256) void k1_agg(
    const float* __restrict__ input, const int* __restrict__ hem,
    const int* __restrict__ subnet, const float* __restrict__ hem_emb,
    const float* __restrict__ subnet_emb, float* __restrict__ gin) {
  int t = blockIdx.x;
  __shared__ float xs[96 * 96];
  __shared__ float al[96 * 48];
  __shared__ float s1[48];
  __shared__ float s2[96 * 48];
  int tid = threadIdx.x;

  for (int o = tid; o < 96 * 96; o += 256) {
    int i = o / 96, d = o % 96;
    xs[o] = input[i * TN + t * 96 + d];
  }
  for (int o = tid; o < 96 * 48; o += 256) {
    int i = o / 48, c = o % 48;
    al[o] = (c < 24) ? hem_emb[hem[i] * 24 + c]
                     : subnet_emb[subnet[i] * 24 + (c - 24)];
  }
  __syncthreads();
  if (tid < 48) {
    float s = 0.f;
    for (int i = 0; i < 96; i++) s += fmaxf(xs[i * 96 + tid] + al[i * 48 + tid], 0.f);
    s1[tid] = s;
  }
  for (int o = tid; o < 96 * 48; o += 256) {
    int j = o / 48, c = o % 48;
    float av = al[j * 48 + c];
    float s = 0.f;
    for (int i = 0; i < 96; i++) s += fmaxf(xs[i * 96 + 48 + c] + av, 0.f);
    s2[o] = s;
  }
  __syncthreads();
  for (int o = tid; o < 96 * 96; o += 256) {
    int j = o / 96, d = o % 96;
    float aggv = (d < 48) ? s1[d] : s2[j * 48 + (d - 48)];
    gin[t * 9216 + o] = xs[o] + aggv;
  }
}

// ---------------------------------------------------------------------------
// K2 (fused MLP + node-batchnorm), one block per t (96 rows = all nodes).
// Register-tiled 6x6 GEMMs; BN reduction is block-local; writes z directly.
// Replaces k2_mlp + k2_bn (saves 5.9MB H write + 5.9MB H read + 1 launch).
// ---------------------------------------------------------------------------
__global__ __launch_bounds__(256) void k2_fused(
    const float* __restrict__ gin, const float* __restrict__ input,
    const float* __restrict__ W1, const float* __restrict__ b1,
    const float* __restrict__ W2, const float* __restrict__ b2,
    const float* __restrict__ bn_w, const float* __restrict__ bn_b,
    float* __restrict__ z) {
  int t = blockIdx.x;
  __shared__ float As[96][100];  // gin tile -> hidden -> pre-BN result
  __shared__ float Bs[96][96];   // W1, then W2
  __shared__ float mu[96], rs[96];
  int tid = threadIdx.x;
  int tx = tid & 15, ty = tid >> 4;
  int c0 = tx * 6;   // 16 col-groups x 6
  int r0 = ty * 6;   // 16 row-groups x 6

  for (int o = tid; o < 9216; o += 256) As[o / 96][o % 96] = gin[(size_t)t * 9216 + o];
  for (int o = tid; o < 9216; o += 256) Bs[o / 96][o % 96] = W1[o];
  __syncthreads();

  float acc[6][6];
#pragma unroll
  for (int i = 0; i < 6; i++)
#pragma unroll
    for (int j = 0; j < 6; j++) acc[i][j] = b1[c0 + j];

#pragma unroll 4
  for (int k = 0; k < 96; k++) {
    float a[6], bv[6];
#pragma unroll
    for (int i = 0; i < 6; i++) a[i] = As[r0 + i][k];
#pragma unroll
    for (int j = 0; j < 6; j++) bv[j] = Bs[k][c0 + j];
#pragma unroll
    for (int i = 0; i < 6; i++)
#pragma unroll
      for (int j = 0; j < 6; j++) acc[i][j] += a[i] * bv[j];
  }
  __syncthreads();  // GEMM1 reads of As/Bs complete

  // hidden (relu) -> As ; W2 -> Bs
#pragma unroll
  for (int i = 0; i < 6; i++)
#pragma unroll
    for (int j = 0; j < 6; j++) As[r0 + i][c0 + j] = fmaxf(acc[i][j], 0.f);
  for (int o = tid; o < 9216; o += 256) Bs[o / 96][o % 96] = W2[o];
#pragma unroll
  for (int i = 0; i < 6; i++)
#pragma unroll
    for (int j = 0; j < 6; j++) acc[i][j] = b2[c0 + j];
  __syncthreads();

#pragma unroll 4
  for (int k = 0; k < 96; k++) {
    float a[6], bv[6];
#pragma unroll
    for (int i = 0; i < 6; i++) a[i] = As[r0 + i][k];
#pragma unroll
    for (int j = 0; j < 6; j++) bv[j] = Bs[k][c0 + j];
#pragma unroll
    for (int i = 0; i < 6; i++)
#pragma unroll
      for (int j = 0; j < 6; j++) acc[i][j] += a[i] * bv[j];
  }
  // + xs residual
#pragma unroll
  for (int i = 0; i < 6; i++) {
    const float* resr = input + (size_t)(r0 + i) * TN + t * 96 + c0;
#pragma unroll
    for (int j = 0; j < 6; j++) acc[i][j] += resr[j];
  }
  __syncthreads();  // GEMM2 reads of As complete before overwrite
#pragma unroll
  for (int i = 0; i < 6; i++)
#pragma unroll
    for (int j = 0; j < 6; j++) As[r0 + i][c0 + j] = acc[i][j];
  __syncthreads();

  if (tid < 96) {
    float m = 0.f;
    for (int j = 0; j < 96; j++) m += As[j][tid];
    m *= (1.f / 96.f);
    float v = 0.f;
    for (int j = 0; j < 96; j++) { float dd = As[j][tid] - m; v += dd * dd; }
    v *= (1.f / 96.f);
    mu[tid] = m;
    rs[tid] = rsqrtf(v + BN_EPS);
  }
  __syncthreads();
  for (int o = tid; o < 9216; o += 256) {
    int j = o / 96, d = o % 96;
    z[(size_t)j * TN + t * 96 + d] = (As[j][d] - mu[d]) * rs[d] * bn_w[d] + bn_b[d];
  }
}

// ---------------------------------------------------------------------------
// K_convW: in_proj fp32 [96][1158] -> transposed bf16 WT [1158][96]
// ---------------------------------------------------------------------------
__global__ __launch_bounds__(256) void k_convW(
    const float* __restrict__ ip, unsigned short* __restrict__ WT) {
  int idx = blockIdx.x * 256 + threadIdx.x;
  if (idx < 96 * D_IN_PROJ) {
    int k = idx / D_IN_PROJ, n = idx - k * D_IN_PROJ;
    WT[(size_t)n * 96 + k] = bf16r(ip[idx]);
  }
}

// ---------------------------------------------------------------------------
// K3: in_proj GEMM via bf16 MFMA -> bf16 zxw [15360][1160] + fp32 dtw [.][6].
// ---------------------------------------------------------------------------
__global__ __launch_bounds__(256) void k3_mfma(
    const float* __restrict__ Z, const unsigned short* __restrict__ WT,
    unsigned short* __restrict__ zxw, float* __restrict__ dtw) {
  int m0 = blockIdx.x * 128;
  int n0 = blockIdx.y * 64;
  __shared__ unsigned short As[128][104];
  __shared__ unsigned short Bs[64][104];
  unsigned short* Cs = &As[0][0];  // 128x64 staging (16KB), aliases As
  int tid = threadIdx.x;
  int lane = tid & 63, w = tid >> 6;

  for (int o = tid; o < 128 * 24; o += 256) {
    int r = o / 24, c4 = (o % 24) * 4;
    float4 v = *(const float4*)&Z[(size_t)(m0 + r) * 96 + c4];
    unsigned int p0 = pack_bf2(v.x, v.y);
    unsigned int p1 = pack_bf2(v.z, v.w);
    *(uint2*)&As[r][c4] = make_uint2(p0, p1);
  }
  for (int o = tid; o < 64 * 12; o += 256) {
    int nr = o / 12, seg = (o % 12) * 8;
    int n = n0 + nr;
    short8 v = {};
    if (n < D_IN_PROJ) v = *(const short8*)&WT[(size_t)n * 96 + seg];
    *(short8*)&Bs[nr][seg] = v;
  }
  __syncthreads();

  int q = lane >> 4, r16 = lane & 15;
  int wm = w * 32;
  f32x4 acc[2][4] = {};

#pragma unroll
  for (int ks = 0; ks < 3; ks++) {
    int k0 = ks * 32 + q * 8;
    short8 a0 = *(const short8*)&As[wm + r16][k0];
    short8 a1 = *(const short8*)&As[wm + 16 + r16][k0];
    short8 b0 = *(const short8*)&Bs[r16][k0];
    short8 b1 = *(const short8*)&Bs[16 + r16][k0];
    short8 b2 = *(const short8*)&Bs[32 + r16][k0];
    short8 b3 = *(const short8*)&Bs[48 + r16][k0];
    acc[0][0] = __builtin_amdgcn_mfma_f32_16x16x32_bf16(a0, b0, acc[0][0], 0, 0, 0);
    acc[0][1] = __builtin_amdgcn_mfma_f32_16x16x32_bf16(a0, b1, acc[0][1], 0, 0, 0);
    acc[0][2] = __builtin_amdgcn_mfma_f32_16x16x32_bf16(a0, b2, acc[0][2], 0, 0, 0);
    acc[0][3] = __builtin_amdgcn_mfma_f32_16x16x32_bf16(a0, b3, acc[0][3], 0, 0, 0);
    acc[1][0] = __builtin_amdgcn_mfma_f32_16x16x32_bf16(a1, b0, acc[1][0], 0, 0, 0);
    acc[1][1] = __builtin_amdgcn_mfma_f32_16x16x32_bf16(a1, b1, acc[1][1], 0, 0, 0);
    acc[1][2] = __builtin_amdgcn_mfma_f32_16x16x32_bf16(a1, b2, acc[1][2], 0, 0, 0);
    acc[1][3] = __builtin_amdgcn_mfma_f32_16x16x32_bf16(a1, b3, acc[1][3], 0, 0, 0);
  }

  __syncthreads();  // all As/Bs reads done before Cs (=As) overwrite

#pragma unroll
  for (int mf = 0; mf < 2; mf++) {
#pragma unroll
    for (int nf = 0; nf < 4; nf++) {
      int col = n0 + nf * 16 + r16;
      int rowb = wm + mf * 16 + q * 4;
#pragma unroll
      for (int reg = 0; reg < 4; reg++) {
        Cs[(rowb + reg) * 64 + nf * 16 + r16] = bf16r(acc[mf][nf][reg]);
        if (col >= 1152 && col < D_IN_PROJ)
          dtw[(size_t)(m0 + rowb + reg) * 6 + (col - 1152)] = acc[mf][nf][reg];
      }
    }
  }
  __syncthreads();

  for (int v = tid; v < 1024; v += 256) {
    int r = v >> 3, seg = (v & 7) * 8;
    if (n0 + seg + 8 <= ZXW_LD)
      *(short8*)&zxw[(size_t)(m0 + r) * ZXW_LD + n0 + seg] =
          *(const short8*)&Cs[r * 64 + seg];
  }
}

// ---------------------------------------------------------------------------
// K5 (fused conv + SSD, R14-measured-best version): 640 threads (10 waves).
// Conv: 160 ch x 4 t-quarters (40 rows each, register halo), scalar bf16
// streaming from zxw, barrier-free. dt from fp32 dtw. XdA fill: one 16B row
// per thread (contiguous ds_write_b128). Wave 0 does the shfl prefix scan
// concurrently. MFMA phase: wave w owns t-tile [16w, 16w+16).
// ---------------------------------------------------------------------------
__global__ __launch_bounds__(640) void k5_fused(
    const unsigned short* __restrict__ zxw, const float* __restrict__ dtw,
    const float* __restrict__ conv_w, const float* __restrict__ conv_b,
    const float* __restrict__ dt_bias, const float* __restrict__ A_log,
    const float* __restrict__ Dparam, float* __restrict__ y) {
  int b = blockIdx.x;  // 96
  int h = blockIdx.y;  // 6
  int tid = threadIdx.x;

  __shared__ __align__(16) unsigned char smem[67840];
  unsigned short* XdA = (unsigned short*)smem;            // 10240 B
  unsigned short* Bb = (unsigned short*)(smem + 10240);   // [160][72] 23040 B
  unsigned short* Cb = (unsigned short*)(smem + 33280);   // [160][72] 23040 B
  unsigned short* xb = (unsigned short*)(smem + 56320);   // [160][32] 10240 B
  float* dt_s = (float*)(smem + 66560);                   // [160]
  float* sc_a = (float*)(smem + 67200);                   // [160]

  float Ah = -expf(A_log[h]);
  float Dh = Dparam[h];
  float dtb = dt_bias[h];
  const unsigned short* zroww = zxw + (size_t)b * 160 * ZXW_LD;

  // ---- conv: thread = (channel cc, t-quarter tq); 40 rows each ----
  {
    int cc = tid % 160, tq = tid / 160;
    int c, csrc;
    if (cc < 32) {
      c = h * 32 + cc;
      csrc = 192 + h * 32 + cc;
    } else if (cc < 96) {
      c = 192 + h * 64 + (cc - 32);
      csrc = 384 + h * 64 + (cc - 32);
    } else {
      c = 576 + h * 64 + (cc - 96);
      csrc = 768 + h * 64 + (cc - 96);
    }
    float cw0 = conv_w[c * 4 + 0], cw1 = conv_w[c * 4 + 1];
    float cw2 = conv_w[c * 4 + 2], cw3 = conv_w[c * 4 + 3];
    float cb = conv_b[c];
    unsigned short* cdst;
    int cstride;
    if (cc < 32)      { cdst = xb + cc;        cstride = 32; }
    else if (cc < 96) { cdst = Bb + (cc - 32); cstride = 72; }
    else              { cdst = Cb + (cc - 96); cstride = 72; }

    float rdt = 0.f;
    if (tid < 160) rdt = dtw[(size_t)(b * 160 + tid) * 6 + h];

    int t0 = tq * 40;
    float h0 = 0.f, h1 = 0.f, h2 = 0.f;
    if (tq > 0) {
      h0 = bf16f(zroww[(size_t)(t0 - 3) * ZXW_LD + csrc]);
      h1 = bf16f(zroww[(size_t)(t0 - 2) * ZXW_LD + csrc]);
      h2 = bf16f(zroww[(size_t)(t0 - 1) * ZXW_LD + csrc]);
    }
#pragma unroll 8
    for (int i = 0; i < 40; i++) {
      int t = t0 + i;
      float d = bf16f(zroww[(size_t)t * ZXW_LD + csrc]);
      float o = cb + h0 * cw0 + h1 * cw1 + h2 * cw2 + d * cw3;
      cdst[t * cstride] = bf16r(siluf(o));
      h0 = h1; h1 = h2; h2 = d;
    }
    if (tid < 160) {
      float dtv = softplusf(rdt + dtb);
      dt_s[tid] = dtv;
      sc_a[tid] = dtv * Ah;
    }
  }
  __syncthreads();  // conv outputs + dt/log-decays visible

  // ---- waves 1-9: XdA fill, one contiguous 16B row per thread ----
  if (tid >= 64) {
    for (int row = tid - 64; row < 640; row += 576) {
      int p = row & 31, qq = (row >> 5) & 3, K = row >> 7;
      short8 v;
#pragma unroll
      for (int j = 0; j < 8; j++) {
        int tau = K * 32 + (j & 3) + 4 * qq + 16 * (j >> 2);
        ((unsigned short*)&v)[j] = bf16r(dt_s[tau] * bf16f(xb[tau * 32 + p]));
      }
      *(short8*)&XdA[row * 8] = v;
    }
  } else {
    // ---- wave 0: inclusive prefix scan of 160 log-decays via shfl ----
    int l = tid;
    float a = sc_a[l];
    float bseg = sc_a[64 + l];
    float cseg = (l < 32) ? sc_a[128 + l] : 0.f;
#pragma unroll
    for (int off = 1; off < 64; off <<= 1) {
      float u = __shfl_up(a, off);
      if (l >= off) a += u;
    }
    float s0 = __shfl(a, 63);
#pragma unroll
    for (int off = 1; off < 64; off <<= 1) {
      float u = __shfl_up(bseg, off);
      if (l >= off) bseg += u;
    }
    bseg += s0;
    float s1 = __shfl(bseg, 63);
#pragma unroll
    for (int off = 1; off < 32; off <<= 1) {
      float u = __shfl_up(cseg, off);
      if (l >= off) cseg += u;
    }
    cseg += s1;
    sc_a[l] = a;
    sc_a[64 + l] = bseg;
    if (l < 32) sc_a[128 + l] = cseg;
  }
  __syncthreads();  // XdA + scanned lc visible
  const float* lc = sc_a;

  // ---- MFMA phase: wave w owns t-tile [16w, 16w+16) ----
  int wid = tid >> 6, lane = tid & 63;
  int q = lane >> 4, r16 = lane & 15;
  int tbase = wid * 16;
  int t = tbase + r16;

  short8 cfr0 = *(const short8*)&Cb[t * 72 + q * 8];
  short8 cfr1 = *(const short8*)&Cb[t * 72 + 32 + q * 8];
  float lct = lc[t];
  f32x4 yacc[2] = {};
  int Kmax = wid >> 1;

  for (int K = 0; K <= Kmax; K++) {
    short8 bfr[2][2];
    f32x4 lc4[2];
#pragma unroll
    for (int i = 0; i < 2; i++) {
      int tr = (2 * K + i) * 16 + r16;
      bfr[i][0] = *(const short8*)&Bb[tr * 72 + q * 8];
      bfr[i][1] = *(const short8*)&Bb[tr * 72 + 32 + q * 8];
      lc4[i] = *(const f32x4*)&lc[(2 * K + i) * 16 + q * 4];
    }
    f32x4 g[2] = {};
#pragma unroll
    for (int i = 0; i < 2; i++) {
      g[i] = __builtin_amdgcn_mfma_f32_16x16x32_bf16(bfr[i][0], cfr0, g[i], 0, 0, 0);
      g[i] = __builtin_amdgcn_mfma_f32_16x16x32_bf16(bfr[i][1], cfr1, g[i], 0, 0, 0);
    }
#pragma unroll
    for (int i = 0; i < 2; i++) {
#pragma unroll
      for (int reg = 0; reg < 4; reg++) {
        int tau = 32 * K + i * 16 + q * 4 + reg;
        float w = (tau <= t) ? __expf(lct - lc4[i][reg]) : 0.f;
        g[i][reg] *= w;
      }
    }
    short8 xfr[2];
#pragma unroll
    for (int mf = 0; mf < 2; mf++)
      xfr[mf] = *(const short8*)&XdA[(((K * 4 + q) << 5) + mf * 16 + r16) * 8];
    union { short8 s; unsigned int u[4]; } sb;
    sb.u[0] = pack_bf2(g[0][0], g[0][1]);
    sb.u[1] = pack_bf2(g[0][2], g[0][3]);
    sb.u[2] = pack_bf2(g[1][0], g[1][1]);
    sb.u[3] = pack_bf2(g[1][2], g[1][3]);
#pragma unroll
    for (int mf = 0; mf < 2; mf++)
      yacc[mf] = __builtin_amdgcn_mfma_f32_16x16x32_bf16(xfr[mf], sb.s, yacc[mf], 0, 0, 0);
  }

  // ---- epilogue: y = yacc + D*x ----
#pragma unroll
  for (int mf = 0; mf < 2; mf++) {
    int p0 = mf * 16 + q * 4;
    float4 o;
    float* op = (float*)&o;
#pragma unroll
    for (int reg = 0; reg < 4; reg++) {
      float xv = bf16f(xb[t * 32 + p0 + reg]);
      op[reg] = yacc[mf][reg] + Dh * xv;
    }
    *(float4*)&y[((size_t)(b * 160 + t)) * D_INNER + h * 32 + p0] = o;
  }
}

// ---------------------------------------------------------------------------
// K6 v2: gated RMSNorm + out_proj + partial time-mean (R15-verified).
// ---------------------------------------------------------------------------
#define K6T 16
#define K6LD 204

__global__ __launch_bounds__(256) void k6_head(
    const float* __restrict__ y, const unsigned short* __restrict__ zxw,
    const float* __restrict__ norm_w, const float* __restrict__ out_proj,
    float* __restrict__ e_part) {
  int b = blockIdx.x;
  int ch = blockIdx.y;  // 10 chunks x 16 timesteps
  int tid = threadIdx.x;
  __shared__ float g[K6T][K6LD];
  __shared__ float rf[K6T];
  __shared__ float nw[192];
  __shared__ float ep[K6T][97];
  int t0 = ch * K6T;

  if (tid < 192) nw[tid] = norm_w[tid];

  for (int v = tid; v < K6T * 24; v += 256) {
    int tt = v / 24, c8 = (v % 24) * 8;
    size_t row = (size_t)(b * 160 + t0 + tt);
    short8 zg8 = *(const short8*)&zxw[row * ZXW_LD + c8];
    float4 y0 = *(const float4*)&y[row * D_INNER + c8];
    float4 y1 = *(const float4*)&y[row * D_INNER + c8 + 4];
    float* yp0 = (float*)&y0;
    float* yp1 = (float*)&y1;
    float4 g0, g1;
    float* gp0 = (float*)&g0;
    float* gp1 = (float*)&g1;
#pragma unroll
    for (int k = 0; k < 4; k++)
      gp0[k] = yp0[k] * siluf(bf16f((unsigned short)zg8[k]));
#pragma unroll
    for (int k = 0; k < 4; k++)
      gp1[k] = yp1[k] * siluf(bf16f((unsigned short)zg8[4 + k]));
    *(float4*)&g[tt][c8] = g0;
    *(float4*)&g[tt][c8 + 4] = g1;
  }
  __syncthreads();

  {
    int tt = tid >> 4, l = tid & 15;
    float ss = 0.f;
    for (int k = l; k < 192; k += 16) {
      float v = g[tt][k];
      ss += v * v;
    }
    ss += __shfl_xor(ss, 1);
    ss += __shfl_xor(ss, 2);
    ss += __shfl_xor(ss, 4);
    ss += __shfl_xor(ss, 8);
    if (l == 0) rf[tt] = rsqrtf(ss * (1.f / 192.f) + RMS_EPS);
  }
  __syncthreads();

  if (tid < 192) {
    int tt = tid & 15, grp = tid >> 4;
    int d0 = grp * 8;
    float rr = rf[tt];
    float acc[8] = {};
    for (int k = 0; k < 192; k += 4) {
      float4 g4 = *(const float4*)&g[tt][k];
      float4 n4 = *(const float4*)&nw[k];
      const float* gp = (const float*)&g4;
      const float* np = (const float*)&n4;
#pragma unroll
      for (int kk = 0; kk < 4; kk++) {
        float gk = gp[kk] * rr * np[kk];
        float4 wv0 = *(const float4*)&out_proj[(size_t)(k + kk) * 96 + d0];
        float4 wv1 = *(const float4*)&out_proj[(size_t)(k + kk) * 96 + d0 + 4];
        acc[0] += gk * wv0.x;
        acc[1] += gk * wv0.y;
        acc[2] += gk * wv0.z;
        acc[3] += gk * wv0.w;
        acc[4] += gk * wv1.x;
        acc[5] += gk * wv1.y;
        acc[6] += gk * wv1.z;
        acc[7] += gk * wv1.w;
      }
    }
#pragma unroll
    for (int j = 0; j < 8; j++) ep[tt][d0 + j] = acc[j];
  }
  __syncthreads();

  if (tid < 96) {
    float sum = 0.f;
#pragma unroll
    for (int tt = 0; tt < K6T; tt++) sum += ep[tt][tid];
    e_part[(size_t)ch * 9216 + b * 96 + tid] = sum;
  }
}

// ---------------------------------------------------------------------------
// K7: reduce chunks, final heads: x1, mu, sigma
// ---------------------------------------------------------------------------
__global__ __launch_bounds__(128) void k7_out(
    const float* __restrict__ e_part, const float* __restrict__ fcw,
    const float* __restrict__ fcb, const float* __restrict__ mu_w,
    const float* __restrict__ mu_b, const float* __restrict__ sg_w,
    const float* __restrict__ sg_b, float* __restrict__ out) {
  int b = blockIdx.x;
  int tid = threadIdx.x;
  __shared__ float em[96];
  __shared__ float x1[96];
  if (tid < 96) {
    float s = 0.f;
    for (int c = 0; c < 10; c++) s += e_part[(size_t)c * 9216 + b * 96 + tid];
    em[tid] = s * (1.f / 160.f);
  }
  __syncthreads();
  if (tid < 96) {
    float acc = fcb[tid];
    for (int k = 0; k < 96; k++) acc += em[k] * fcw[k * 96 + tid];
    float tv = tanhf(acc);
    float ev = (tv > 0.f) ? tv : expm1f(tv);
    x1[tid] = ev;
    out[b * 96 + tid] = ev;
  }
  __syncthreads();
  int j = tid & 63, which = tid >> 6;
  if (which == 0) {
    float acc = mu_b[j];
    for (int k = 0; k < 96; k++) acc += x1[k] * mu_w[k * 64 + j];
    out[9216 + b * 64 + j] = acc;
  } else {
    float acc = sg_b[j];
    for (int k = 0; k < 96; k++) acc += x1[k] * sg_w[k * 64 + j];
    float ev = (acc > 0.f) ? acc : expm1f(acc);
    out[9216 + 6144 + b * 64 + j] = ev + 1.f + 1e-14f;
  }
}

// ---------------------------------------------------------------------------
extern "C" void kernel_launch(void* const* d_in, const int* in_sizes, int n_in,
                              void* d_out, int out_size, void* d_ws,
                              size_t ws_size, hipStream_t stream) {
  const float* input      = (const float*)d_in[0];
  const int*   hem        = (const int*)d_in[1];
  const int*   subnet     = (const int*)d_in[2];
  const float* gine_w1    = (const float*)d_in[3];
  const float* gine_b1    = (const float*)d_in[4];
  const float* gine_w2    = (const float*)d_in[5];
  const float* gine_b2    = (const float*)d_in[6];
  const float* bn_w       = (const float*)d_in[7];
  const float* bn_b       = (const float*)d_in[8];
  const float* hem_emb    = (const float*)d_in[9];
  const float* subnet_emb = (const float*)d_in[10];
  const float* in_proj    = (const float*)d_in[11];
  const float* conv_w     = (const float*)d_in[12];
  const float* conv_b     = (const float*)d_in[13];
  const float* dt_bias    = (const float*)d_in[14];
  const float* A_log      = (const float*)d_in[15];
  const float* Dparam     = (const float*)d_in[16];
  const float* norm_w     = (const float*)d_in[17];
  const float* out_proj   = (const float*)d_in[18];
  const float* out_fc_w   = (const float*)d_in[19];
  const float* out_fc_b   = (const float*)d_in[20];
  const float* mu_w       = (const float*)d_in[21];
  const float* mu_b       = (const float*)d_in[22];
  const float* sigma_w    = (const float*)d_in[23];
  const float* sigma_b    = (const float*)d_in[24];

  float* ws = (float*)d_ws;
  float* gin    = ws;                  // 1,474,560
  float* z      = gin + 1474560;       // 1,474,560
  float* zxf    = z + 1474560;         // 17,786,880 fp32 slots -> holds bf16 zxw
  float* y      = zxf + 17786880;      // 2,949,120
  float* e_part = y + 2949120;         // 92,160 (10 chunks)
  float* dtw    = e_part + 92160;      // 92,160 (15360 x 6 fp32 dt)
  unsigned short* zxw = (unsigned short*)zxf;  // [15360][1160] bf16
  // WT (bf16 in_proj^T) aliases the TAIL of y: convW -> k3 -> k5 (overwrites y)
  unsigned short* WT = (unsigned short*)(y + 2893536);
  float* outp = (float*)d_out;

  k_convW<<<435, 256, 0, stream>>>(in_proj, WT);
  k1_agg<<<160, 256, 0, stream>>>(input, hem, subnet, hem_emb, subnet_emb, gin);
  k2_fused<<<160, 256, 0, stream>>>(gin, input, gine_w1, gine_b1, gine_w2,
                                    gine_b2, bn_w, bn_b, z);
  k3_mfma<<<dim3(120, 19), 256, 0, stream>>>(z, WT, zxw, dtw);
  k5_fused<<<dim3(96, 6), 640, 0, stream>>>(zxw, dtw, conv_w, conv_b, dt_bias,
                                            A_log, Dparam, y);
  k6_head<<<dim3(96, 10), 256, 0, stream>>>(y, zxw, norm_w, out_proj, e_part);
  k7_out<<<96, 128, 0, stream>>>(e_part, out_fc_w, out_fc_b, mu_w, mu_b,
                                 sigma_w, sigma_b, outp);
}

// Round 19
// 154.414 us; speedup vs baseline: 1.0595x; 1.0595x over previous
//
#include <hip/hip_runtime.h>
#include <hip/hip_bf16.h>
#include <math.h>

// Problem constants
#define NB 96        // batch / nodes
#define TT 160       // sequence length
#define DD 96        // feature dim
#define D_STATE 64
#define D_CONV 4
#define HEADDIM 32
#define NGROUPS 6
#define D_INNER 192
#define NHEADS 6
#define EMB 24
#define DOUT 64
#define D_IN_PROJ 1158
#define ZXW_LD 1160  // bf16 zxbcdt row stride (shorts), cols 1158/1159 = pad
#define CONV_DIM 960
#define TN 15360     // TT*DD = input row stride per node, also rows of z
#define BN_EPS 1e-5f
#define RMS_EPS 1e-5f

typedef __attribute__((ext_vector_type(8))) short short8;
typedef __attribute__((ext_vector_type(4))) float f32x4;

__device__ __forceinline__ float siluf(float x) { return x / (1.f + expf(-x)); }
__device__ __forceinline__ float softplusf(float x) {
    return fmaxf(x, 0.f) + log1pf(expf(-fabsf(x)));
}
__device__ __forceinline__ unsigned short bf16r(float x) {
  union { __hip_bfloat16 h; unsigned short u; } cv;
  cv.h = __float2bfloat16(x);
  return cv.u;
}
__device__ __forceinline__ unsigned int pack_bf2(float a, float b) {
  return (unsigned int)bf16r(a) | ((unsigned int)bf16r(b) << 16);
}
__device__ __forceinline__ float bf16f(unsigned short u) {
  return __uint_as_float((unsigned int)u << 16);
}

// ---------------------------------------------------------------------------
// K1 (merged): blocks 0..159 do per-t aggregation; blocks 160.. do the
// in_proj -> bf16 WT transpose (independent work, saves one launch).
// ---------------------------------------------------------------------------
__global__ __launch_bounds__(256) void k1_agg(
    const float* __restrict__ input, const int* __restrict__ hem,
    const int* __restrict__ subnet, const float* __restrict__ hem_emb,
    const float* __restrict__ subnet_emb, float* __restrict__ gin,
    const float* __restrict__ ip, unsigned short* __restrict__ WT) {
  int tid = threadIdx.x;
  if (blockIdx.x >= 160) {
    int idx = (blockIdx.x - 160) * 256 + tid;
    if (idx < 96 * D_IN_PROJ) {
      int k = idx / D_IN_PROJ, n = idx - k * D_IN_PROJ;
      WT[(size_t)n * 96 + k] = bf16r(ip[idx]);
    }
    return;
  }
  int t = blockIdx.x;
  __shared__ float xs[96 * 96];
  __shared__ float al[96 * 48];
  __shared__ float s1[48];
  __shared__ float s2[96 * 48];

  for (int o = tid; o < 96 * 96; o += 256) {
    int i = o / 96, d = o % 96;
    xs[o] = input[i * TN + t * 96 + d];
  }
  for (int o = tid; o < 96 * 48; o += 256) {
    int i = o / 48, c = o % 48;
    al[o] = (c < 24) ? hem_emb[hem[i] * 24 + c]
                     : subnet_emb[subnet[i] * 24 + (c - 24)];
  }
  __syncthreads();
  if (tid < 48) {
    float s = 0.f;
    for (int i = 0; i < 96; i++) s += fmaxf(xs[i * 96 + tid] + al[i * 48 + tid], 0.f);
    s1[tid] = s;
  }
  for (int o = tid; o < 96 * 48; o += 256) {
    int j = o / 48, c = o % 48;
    float av = al[j * 48 + c];
    float s = 0.f;
    for (int i = 0; i < 96; i++) s += fmaxf(xs[i * 96 + 48 + c] + av, 0.f);
    s2[o] = s;
  }
  __syncthreads();
  for (int o = tid; o < 96 * 96; o += 256) {
    int j = o / 96, d = o % 96;
    float aggv = (d < 48) ? s1[d] : s2[j * 48 + (d - 48)];
    gin[t * 9216 + o] = xs[o] + aggv;
  }
}

// ---------------------------------------------------------------------------
// K2 (fused MLP + node-batchnorm), one block per t (96 rows = all nodes).
// ---------------------------------------------------------------------------
__global__ __launch_bounds__(256) void k2_fused(
    const float* __restrict__ gin, const float* __restrict__ input,
    const float* __restrict__ W1, const float* __restrict__ b1,
    const float* __restrict__ W2, const float* __restrict__ b2,
    const float* __restrict__ bn_w, const float* __restrict__ bn_b,
    float* __restrict__ z) {
  int t = blockIdx.x;
  __shared__ float As[96][100];
  __shared__ float Bs[96][96];
  __shared__ float mu[96], rs[96];
  int tid = threadIdx.x;
  int tx = tid & 15, ty = tid >> 4;
  int c0 = tx * 6;
  int r0 = ty * 6;

  for (int o = tid; o < 9216; o += 256) As[o / 96][o % 96] = gin[(size_t)t * 9216 + o];
  for (int o = tid; o < 9216; o += 256) Bs[o / 96][o % 96] = W1[o];
  __syncthreads();

  float acc[6][6];
#pragma unroll
  for (int i = 0; i < 6; i++)
#pragma unroll
    for (int j = 0; j < 6; j++) acc[i][j] = b1[c0 + j];

#pragma unroll 4
  for (int k = 0; k < 96; k++) {
    float a[6], bv[6];
#pragma unroll
    for (int i = 0; i < 6; i++) a[i] = As[r0 + i][k];
#pragma unroll
    for (int j = 0; j < 6; j++) bv[j] = Bs[k][c0 + j];
#pragma unroll
    for (int i = 0; i < 6; i++)
#pragma unroll
      for (int j = 0; j < 6; j++) acc[i][j] += a[i] * bv[j];
  }
  __syncthreads();

#pragma unroll
  for (int i = 0; i < 6; i++)
#pragma unroll
    for (int j = 0; j < 6; j++) As[r0 + i][c0 + j] = fmaxf(acc[i][j], 0.f);
  for (int o = tid; o < 9216; o += 256) Bs[o / 96][o % 96] = W2[o];
#pragma unroll
  for (int i = 0; i < 6; i++)
#pragma unroll
    for (int j = 0; j < 6; j++) acc[i][j] = b2[c0 + j];
  __syncthreads();

#pragma unroll 4
  for (int k = 0; k < 96; k++) {
    float a[6], bv[6];
#pragma unroll
    for (int i = 0; i < 6; i++) a[i] = As[r0 + i][k];
#pragma unroll
    for (int j = 0; j < 6; j++) bv[j] = Bs[k][c0 + j];
#pragma unroll
    for (int i = 0; i < 6; i++)
#pragma unroll
      for (int j = 0; j < 6; j++) acc[i][j] += a[i] * bv[j];
  }
#pragma unroll
  for (int i = 0; i < 6; i++) {
    const float* resr = input + (size_t)(r0 + i) * TN + t * 96 + c0;
#pragma unroll
    for (int j = 0; j < 6; j++) acc[i][j] += resr[j];
  }
  __syncthreads();
#pragma unroll
  for (int i = 0; i < 6; i++)
#pragma unroll
    for (int j = 0; j < 6; j++) As[r0 + i][c0 + j] = acc[i][j];
  __syncthreads();

  if (tid < 96) {
    float m = 0.f;
    for (int j = 0; j < 96; j++) m += As[j][tid];
    m *= (1.f / 96.f);
    float v = 0.f;
    for (int j = 0; j < 96; j++) { float dd = As[j][tid] - m; v += dd * dd; }
    v *= (1.f / 96.f);
    mu[tid] = m;
    rs[tid] = rsqrtf(v + BN_EPS);
  }
  __syncthreads();
  for (int o = tid; o < 9216; o += 256) {
    int j = o / 96, d = o % 96;
    z[(size_t)j * TN + t * 96 + d] = (As[j][d] - mu[d]) * rs[d] * bn_w[d] + bn_b[d];
  }
}

// ---------------------------------------------------------------------------
// K3: in_proj GEMM via bf16 MFMA -> bf16 zxw [15360][1160] + fp32 dtw [.][6].
// ---------------------------------------------------------------------------
__global__ __launch_bounds__(256) void k3_mfma(
    const float* __restrict__ Z, const unsigned short* __restrict__ WT,
    unsigned short* __restrict__ zxw, float* __restrict__ dtw) {
  int m0 = blockIdx.x * 128;
  int n0 = blockIdx.y * 64;
  __shared__ unsigned short As[128][104];
  __shared__ unsigned short Bs[64][104];
  unsigned short* Cs = &As[0][0];  // 128x64 staging (16KB), aliases As
  int tid = threadIdx.x;
  int lane = tid & 63, w = tid >> 6;

  for (int o = tid; o < 128 * 24; o += 256) {
    int r = o / 24, c4 = (o % 24) * 4;
    float4 v = *(const float4*)&Z[(size_t)(m0 + r) * 96 + c4];
    unsigned int p0 = pack_bf2(v.x, v.y);
    unsigned int p1 = pack_bf2(v.z, v.w);
    *(uint2*)&As[r][c4] = make_uint2(p0, p1);
  }
  for (int o = tid; o < 64 * 12; o += 256) {
    int nr = o / 12, seg = (o % 12) * 8;
    int n = n0 + nr;
    short8 v = {};
    if (n < D_IN_PROJ) v = *(const short8*)&WT[(size_t)n * 96 + seg];
    *(short8*)&Bs[nr][seg] = v;
  }
  __syncthreads();

  int q = lane >> 4, r16 = lane & 15;
  int wm = w * 32;
  f32x4 acc[2][4] = {};

#pragma unroll
  for (int ks = 0; ks < 3; ks++) {
    int k0 = ks * 32 + q * 8;
    short8 a0 = *(const short8*)&As[wm + r16][k0];
    short8 a1 = *(const short8*)&As[wm + 16 + r16][k0];
    short8 b0 = *(const short8*)&Bs[r16][k0];
    short8 b1 = *(const short8*)&Bs[16 + r16][k0];
    short8 b2 = *(const short8*)&Bs[32 + r16][k0];
    short8 b3 = *(const short8*)&Bs[48 + r16][k0];
    acc[0][0] = __builtin_amdgcn_mfma_f32_16x16x32_bf16(a0, b0, acc[0][0], 0, 0, 0);
    acc[0][1] = __builtin_amdgcn_mfma_f32_16x16x32_bf16(a0, b1, acc[0][1], 0, 0, 0);
    acc[0][2] = __builtin_amdgcn_mfma_f32_16x16x32_bf16(a0, b2, acc[0][2], 0, 0, 0);
    acc[0][3] = __builtin_amdgcn_mfma_f32_16x16x32_bf16(a0, b3, acc[0][3], 0, 0, 0);
    acc[1][0] = __builtin_amdgcn_mfma_f32_16x16x32_bf16(a1, b0, acc[1][0], 0, 0, 0);
    acc[1][1] = __builtin_amdgcn_mfma_f32_16x16x32_bf16(a1, b1, acc[1][1], 0, 0, 0);
    acc[1][2] = __builtin_amdgcn_mfma_f32_16x16x32_bf16(a1, b2, acc[1][2], 0, 0, 0);
    acc[1][3] = __builtin_amdgcn_mfma_f32_16x16x32_bf16(a1, b3, acc[1][3], 0, 0, 0);
  }

  __syncthreads();  // all As/Bs reads done before Cs (=As) overwrite

#pragma unroll
  for (int mf = 0; mf < 2; mf++) {
#pragma unroll
    for (int nf = 0; nf < 4; nf++) {
      int col = n0 + nf * 16 + r16;
      int rowb = wm + mf * 16 + q * 4;
#pragma unroll
      for (int reg = 0; reg < 4; reg++) {
        Cs[(rowb + reg) * 64 + nf * 16 + r16] = bf16r(acc[mf][nf][reg]);
        if (col >= 1152 && col < D_IN_PROJ)
          dtw[(size_t)(m0 + rowb + reg) * 6 + (col - 1152)] = acc[mf][nf][reg];
      }
    }
  }
  __syncthreads();

  for (int v = tid; v < 1024; v += 256) {
    int r = v >> 3, seg = (v & 7) * 8;
    if (n0 + seg + 8 <= ZXW_LD)
      *(short8*)&zxw[(size_t)(m0 + r) * ZXW_LD + n0 + seg] =
          *(const short8*)&Cs[r * 64 + seg];
  }
}

// ---------------------------------------------------------------------------
// K5 (fused conv + SSD, R14-measured-best version, unchanged).
// ---------------------------------------------------------------------------
__global__ __launch_bounds__(640) void k5_fused(
    const unsigned short* __restrict__ zxw, const float* __restrict__ dtw,
    const float* __restrict__ conv_w, const float* __restrict__ conv_b,
    const float* __restrict__ dt_bias, const float* __restrict__ A_log,
    const float* __restrict__ Dparam, float* __restrict__ y) {
  int b = blockIdx.x;  // 96
  int h = blockIdx.y;  // 6
  int tid = threadIdx.x;

  __shared__ __align__(16) unsigned char smem[67840];
  unsigned short* XdA = (unsigned short*)smem;            // 10240 B
  unsigned short* Bb = (unsigned short*)(smem + 10240);   // [160][72] 23040 B
  unsigned short* Cb = (unsigned short*)(smem + 33280);   // [160][72] 23040 B
  unsigned short* xb = (unsigned short*)(smem + 56320);   // [160][32] 10240 B
  float* dt_s = (float*)(smem + 66560);                   // [160]
  float* sc_a = (float*)(smem + 67200);                   // [160]

  float Ah = -expf(A_log[h]);
  float Dh = Dparam[h];
  float dtb = dt_bias[h];
  const unsigned short* zroww = zxw + (size_t)b * 160 * ZXW_LD;

  {
    int cc = tid % 160, tq = tid / 160;
    int c, csrc;
    if (cc < 32) {
      c = h * 32 + cc;
      csrc = 192 + h * 32 + cc;
    } else if (cc < 96) {
      c = 192 + h * 64 + (cc - 32);
      csrc = 384 + h * 64 + (cc - 32);
    } else {
      c = 576 + h * 64 + (cc - 96);
      csrc = 768 + h * 64 + (cc - 96);
    }
    float cw0 = conv_w[c * 4 + 0], cw1 = conv_w[c * 4 + 1];
    float cw2 = conv_w[c * 4 + 2], cw3 = conv_w[c * 4 + 3];
    float cb = conv_b[c];
    unsigned short* cdst;
    int cstride;
    if (cc < 32)      { cdst = xb + cc;        cstride = 32; }
    else if (cc < 96) { cdst = Bb + (cc - 32); cstride = 72; }
    else              { cdst = Cb + (cc - 96); cstride = 72; }

    float rdt = 0.f;
    if (tid < 160) rdt = dtw[(size_t)(b * 160 + tid) * 6 + h];

    int t0 = tq * 40;
    float h0 = 0.f, h1 = 0.f, h2 = 0.f;
    if (tq > 0) {
      h0 = bf16f(zroww[(size_t)(t0 - 3) * ZXW_LD + csrc]);
      h1 = bf16f(zroww[(size_t)(t0 - 2) * ZXW_LD + csrc]);
      h2 = bf16f(zroww[(size_t)(t0 - 1) * ZXW_LD + csrc]);
    }
#pragma unroll 8
    for (int i = 0; i < 40; i++) {
      int t = t0 + i;
      float d = bf16f(zroww[(size_t)t * ZXW_LD + csrc]);
      float o = cb + h0 * cw0 + h1 * cw1 + h2 * cw2 + d * cw3;
      cdst[t * cstride] = bf16r(siluf(o));
      h0 = h1; h1 = h2; h2 = d;
    }
    if (tid < 160) {
      float dtv = softplusf(rdt + dtb);
      dt_s[tid] = dtv;
      sc_a[tid] = dtv * Ah;
    }
  }
  __syncthreads();

  if (tid >= 64) {
    for (int row = tid - 64; row < 640; row += 576) {
      int p = row & 31, qq = (row >> 5) & 3, K = row >> 7;
      short8 v;
#pragma unroll
      for (int j = 0; j < 8; j++) {
        int tau = K * 32 + (j & 3) + 4 * qq + 16 * (j >> 2);
        ((unsigned short*)&v)[j] = bf16r(dt_s[tau] * bf16f(xb[tau * 32 + p]));
      }
      *(short8*)&XdA[row * 8] = v;
    }
  } else {
    int l = tid;
    float a = sc_a[l];
    float bseg = sc_a[64 + l];
    float cseg = (l < 32) ? sc_a[128 + l] : 0.f;
#pragma unroll
    for (int off = 1; off < 64; off <<= 1) {
      float u = __shfl_up(a, off);
      if (l >= off) a += u;
    }
    float s0 = __shfl(a, 63);
#pragma unroll
    for (int off = 1; off < 64; off <<= 1) {
      float u = __shfl_up(bseg, off);
      if (l >= off) bseg += u;
    }
    bseg += s0;
    float s1 = __shfl(bseg, 63);
#pragma unroll
    for (int off = 1; off < 32; off <<= 1) {
      float u = __shfl_up(cseg, off);
      if (l >= off) cseg += u;
    }
    cseg += s1;
    sc_a[l] = a;
    sc_a[64 + l] = bseg;
    if (l < 32) sc_a[128 + l] = cseg;
  }
  __syncthreads();
  const float* lc = sc_a;

  int wid = tid >> 6, lane = tid & 63;
  int q = lane >> 4, r16 = lane & 15;
  int tbase = wid * 16;
  int t = tbase + r16;

  short8 cfr0 = *(const short8*)&Cb[t * 72 + q * 8];
  short8 cfr1 = *(const short8*)&Cb[t * 72 + 32 + q * 8];
  float lct = lc[t];
  f32x4 yacc[2] = {};
  int Kmax = wid >> 1;

  for (int K = 0; K <= Kmax; K++) {
    short8 bfr[2][2];
    f32x4 lc4[2];
#pragma unroll
    for (int i = 0; i < 2; i++) {
      int tr = (2 * K + i) * 16 + r16;
      bfr[i][0] = *(const short8*)&Bb[tr * 72 + q * 8];
      bfr[i][1] = *(const short8*)&Bb[tr * 72 + 32 + q * 8];
      lc4[i] = *(const f32x4*)&lc[(2 * K + i) * 16 + q * 4];
    }
    f32x4 g[2] = {};
#pragma unroll
    for (int i = 0; i < 2; i++) {
      g[i] = __builtin_amdgcn_mfma_f32_16x16x32_bf16(bfr[i][0], cfr0, g[i], 0, 0, 0);
      g[i] = __builtin_amdgcn_mfma_f32_16x16x32_bf16(bfr[i][1], cfr1, g[i], 0, 0, 0);
    }
#pragma unroll
    for (int i = 0; i < 2; i++) {
#pragma unroll
      for (int reg = 0; reg < 4; reg++) {
        int tau = 32 * K + i * 16 + q * 4 + reg;
        float w = (tau <= t) ? __expf(lct - lc4[i][reg]) : 0.f;
        g[i][reg] *= w;
      }
    }
    short8 xfr[2];
#pragma unroll
    for (int mf = 0; mf < 2; mf++)
      xfr[mf] = *(const short8*)&XdA[(((K * 4 + q) << 5) + mf * 16 + r16) * 8];
    union { short8 s; unsigned int u[4]; } sb;
    sb.u[0] = pack_bf2(g[0][0], g[0][1]);
    sb.u[1] = pack_bf2(g[0][2], g[0][3]);
    sb.u[2] = pack_bf2(g[1][0], g[1][1]);
    sb.u[3] = pack_bf2(g[1][2], g[1][3]);
#pragma unroll
    for (int mf = 0; mf < 2; mf++)
      yacc[mf] = __builtin_amdgcn_mfma_f32_16x16x32_bf16(xfr[mf], sb.s, yacc[mf], 0, 0, 0);
  }

#pragma unroll
  for (int mf = 0; mf < 2; mf++) {
    int p0 = mf * 16 + q * 4;
    float4 o;
    float* op = (float*)&o;
#pragma unroll
    for (int reg = 0; reg < 4; reg++) {
      float xv = bf16f(xb[t * 32 + p0 + reg]);
      op[reg] = yacc[mf][reg] + Dh * xv;
    }
    *(float4*)&y[((size_t)(b * 160 + t)) * D_INNER + h * 32 + p0] = o;
  }
}

// ---------------------------------------------------------------------------
// K6 v3: gated RMSNorm + out_proj + partial time-mean.
// out_proj staged ONCE per block as bf16 in LDS (36.9KB) -> GEMM reads LDS
// broadcast instead of re-reading 1.18MB of out_proj from L2 per block.
// ---------------------------------------------------------------------------
#define K6T 16
#define K6LD 204

__global__ __launch_bounds__(256) void k6_head(
    const float* __restrict__ y, const unsigned short* __restrict__ zxw,
    const float* __restrict__ norm_w, const float* __restrict__ out_proj,
    float* __restrict__ e_part) {
  int b = blockIdx.x;
  int ch = blockIdx.y;  // 10 chunks x 16 timesteps
  int tid = threadIdx.x;
  __shared__ float g[K6T][K6LD];
  __shared__ float rf[K6T];
  __shared__ float nw[192];
  __shared__ float ep[K6T][97];
  __shared__ unsigned short opj[192 * 96];  // bf16 out_proj, 36864 B
  int t0 = ch * K6T;

  if (tid < 192) nw[tid] = norm_w[tid];

  // stage out_proj -> bf16 LDS (18432 elems, float4 -> 4x bf16 per step)
  for (int o = tid; o < 4608; o += 256) {
    float4 v = *(const float4*)&out_proj[o * 4];
    unsigned int p0 = pack_bf2(v.x, v.y);
    unsigned int p1 = pack_bf2(v.z, v.w);
    *(uint2*)&opj[o * 4] = make_uint2(p0, p1);
  }

  // phase 1: g = y * silu(zg)
  for (int v = tid; v < K6T * 24; v += 256) {
    int tt = v / 24, c8 = (v % 24) * 8;
    size_t row = (size_t)(b * 160 + t0 + tt);
    short8 zg8 = *(const short8*)&zxw[row * ZXW_LD + c8];
    float4 y0 = *(const float4*)&y[row * D_INNER + c8];
    float4 y1 = *(const float4*)&y[row * D_INNER + c8 + 4];
    float* yp0 = (float*)&y0;
    float* yp1 = (float*)&y1;
    float4 g0, g1;
    float* gp0 = (float*)&g0;
    float* gp1 = (float*)&g1;
#pragma unroll
    for (int k = 0; k < 4; k++)
      gp0[k] = yp0[k] * siluf(bf16f((unsigned short)zg8[k]));
#pragma unroll
    for (int k = 0; k < 4; k++)
      gp1[k] = yp1[k] * siluf(bf16f((unsigned short)zg8[4 + k]));
    *(float4*)&g[tt][c8] = g0;
    *(float4*)&g[tt][c8 + 4] = g1;
  }
  __syncthreads();

  // phase 2: rms factor per t
  {
    int tt = tid >> 4, l = tid & 15;
    float ss = 0.f;
    for (int k = l; k < 192; k += 16) {
      float v = g[tt][k];
      ss += v * v;
    }
    ss += __shfl_xor(ss, 1);
    ss += __shfl_xor(ss, 2);
    ss += __shfl_xor(ss, 4);
    ss += __shfl_xor(ss, 8);
    if (l == 0) rf[tt] = rsqrtf(ss * (1.f / 192.f) + RMS_EPS);
  }
  __syncthreads();

  // phase 3+4 fused: GEMM from LDS (opj broadcast; inline rf*nw scaling)
  if (tid < 192) {
    int tt = tid & 15, grp = tid >> 4;
    int d0 = grp * 8;
    float rr = rf[tt];
    float acc[8] = {};
    for (int k = 0; k < 192; k += 4) {
      float4 g4 = *(const float4*)&g[tt][k];
      float4 n4 = *(const float4*)&nw[k];
      const float* gp = (const float*)&g4;
      const float* np = (const float*)&n4;
#pragma unroll
      for (int kk = 0; kk < 4; kk++) {
        float gk = gp[kk] * rr * np[kk];
        short8 w8 = *(const short8*)&opj[(k + kk) * 96 + d0];
#pragma unroll
        for (int j = 0; j < 8; j++)
          acc[j] += gk * bf16f((unsigned short)w8[j]);
      }
    }
#pragma unroll
    for (int j = 0; j < 8; j++) ep[tt][d0 + j] = acc[j];
  }
  __syncthreads();

  // phase 5: reduce over the 16 t's, write partial sum
  if (tid < 96) {
    float sum = 0.f;
#pragma unroll
    for (int tt = 0; tt < K6T; tt++) sum += ep[tt][tid];
    e_part[(size_t)ch * 9216 + b * 96 + tid] = sum;
  }
}

// ---------------------------------------------------------------------------
// K7: reduce chunks, final heads: x1, mu, sigma
// ---------------------------------------------------------------------------
__global__ __launch_bounds__(128) void k7_out(
    const float* __restrict__ e_part, const float* __restrict__ fcw,
    const float* __restrict__ fcb, const float* __restrict__ mu_w,
    const float* __restrict__ mu_b, const float* __restrict__ sg_w,
    const float* __restrict__ sg_b, float* __restrict__ out) {
  int b = blockIdx.x;
  int tid = threadIdx.x;
  __shared__ float em[96];
  __shared__ float x1[96];
  if (tid < 96) {
    float s = 0.f;
    for (int c = 0; c < 10; c++) s += e_part[(size_t)c * 9216 + b * 96 + tid];
    em[tid] = s * (1.f / 160.f);
  }
  __syncthreads();
  if (tid < 96) {
    float acc = fcb[tid];
    for (int k = 0; k < 96; k++) acc += em[k] * fcw[k * 96 + tid];
    float tv = tanhf(acc);
    float ev = (tv > 0.f) ? tv : expm1f(tv);
    x1[tid] = ev;
    out[b * 96 + tid] = ev;
  }
  __syncthreads();
  int j = tid & 63, which = tid >> 6;
  if (which == 0) {
    float acc = mu_b[j];
    for (int k = 0; k < 96; k++) acc += x1[k] * mu_w[k * 64 + j];
    out[9216 + b * 64 + j] = acc;
  } else {
    float acc = sg_b[j];
    for (int k = 0; k < 96; k++) acc += x1[k] * sg_w[k * 64 + j];
    float ev = (acc > 0.f) ? acc : expm1f(acc);
    out[9216 + 6144 + b * 64 + j] = ev + 1.f + 1e-14f;
  }
}

// ---------------------------------------------------------------------------
extern "C" void kernel_launch(void* const* d_in, const int* in_sizes, int n_in,
                              void* d_out, int out_size, void* d_ws,
                              size_t ws_size, hipStream_t stream) {
  const float* input      = (const float*)d_in[0];
  const int*   hem        = (const int*)d_in[1];
  const int*   subnet     = (const int*)d_in[2];
  const float* gine_w1    = (const float*)d_in[3];
  const float* gine_b1    = (const float*)d_in[4];
  const float* gine_w2    = (const float*)d_in[5];
  const float* gine_b2    = (const float*)d_in[6];
  const float* bn_w       = (const float*)d_in[7];
  const float* bn_b       = (const float*)d_in[8];
  const float* hem_emb    = (const float*)d_in[9];
  const float* subnet_emb = (const float*)d_in[10];
  const float* in_proj    = (const float*)d_in[11];
  const float* conv_w     = (const float*)d_in[12];
  const float* conv_b     = (const float*)d_in[13];
  const float* dt_bias    = (const float*)d_in[14];
  const float* A_log      = (const float*)d_in[15];
  const float* Dparam     = (const float*)d_in[16];
  const float* norm_w     = (const float*)d_in[17];
  const float* out_proj   = (const float*)d_in[18];
  const float* out_fc_w   = (const float*)d_in[19];
  const float* out_fc_b   = (const float*)d_in[20];
  const float* mu_w       = (const float*)d_in[21];
  const float* mu_b       = (const float*)d_in[22];
  const float* sigma_w    = (const float*)d_in[23];
  const float* sigma_b    = (const float*)d_in[24];

  float* ws = (float*)d_ws;
  float* gin    = ws;                  // 1,474,560
  float* z      = gin + 1474560;       // 1,474,560
  float* zxf    = z + 1474560;         // 17,786,880 fp32 slots -> holds bf16 zxw
  float* y      = zxf + 17786880;      // 2,949,120
  float* e_part = y + 2949120;         // 92,160 (10 chunks)
  float* dtw    = e_part + 92160;      // 92,160 (15360 x 6 fp32 dt)
  unsigned short* zxw = (unsigned short*)zxf;  // [15360][1160] bf16
  // WT (bf16 in_proj^T) aliases the TAIL of y: k1(WT) -> k3 -> k5 (overwrites y)
  unsigned short* WT = (unsigned short*)(y + 2893536);
  float* outp = (float*)d_out;

  k1_agg<<<595, 256, 0, stream>>>(input, hem, subnet, hem_emb, subnet_emb,
                                  gin, in_proj, WT);
  k2_fused<<<160, 256, 0, stream>>>(gin, input, gine_w1, gine_b1, gine_w2,
                                    gine_b2, bn_w, bn_b, z);
  k3_mfma<<<dim3(120, 19), 256, 0, stream>>>(z, WT, zxw, dtw);
  k5_fused<<<dim3(96, 6), 640, 0, stream>>>(zxw, dtw, conv_w, conv_b, dt_bias,
                                            A_log, Dparam, y);
  k6_head<<<dim3(96, 10), 256, 0, stream>>>(y, zxw, norm_w, out_proj, e_part);
  k7_out<<<96, 128, 0, stream>>>(e_part, out_fc_w, out_fc_b, mu_w, mu_b,
                                 sigma_w, sigma_b, outp);
}

// Round 20
// 152.032 us; speedup vs baseline: 1.0761x; 1.0157x over previous
//
#include <hip/hip_runtime.h>
#include <hip/hip_bf16.h>
#include <math.h>

// Problem constants
#define NB 96        // batch / nodes
#define TT 160       // sequence length
#define DD 96        // feature dim
#define D_STATE 64
#define D_CONV 4
#define HEADDIM 32
#define NGROUPS 6
#define D_INNER 192
#define NHEADS 6
#define EMB 24
#define DOUT 64
#define D_IN_PROJ 1158
#define ZXW_LD 1160  // bf16 zxbcdt row stride (shorts), cols 1158/1159 = pad
#define CONV_DIM 960
#define TN 15360     // TT*DD = input row stride per node, also rows of z
#define BN_EPS 1e-5f
#define RMS_EPS 1e-5f

typedef __attribute__((ext_vector_type(8))) short short8;
typedef __attribute__((ext_vector_type(4))) float f32x4;

__device__ __forceinline__ float siluf(float x) { return x / (1.f + expf(-x)); }
__device__ __forceinline__ float softplusf(float x) {
    return fmaxf(x, 0.f) + log1pf(expf(-fabsf(x)));
}
__device__ __forceinline__ unsigned short bf16r(float x) {
  union { __hip_bfloat16 h; unsigned short u; } cv;
  cv.h = __float2bfloat16(x);
  return cv.u;
}
__device__ __forceinline__ unsigned int pack_bf2(float a, float b) {
  return (unsigned int)bf16r(a) | ((unsigned int)bf16r(b) << 16);
}
__device__ __forceinline__ float bf16f(unsigned short u) {
  return __uint_as_float((unsigned int)u << 16);
}

// ---------------------------------------------------------------------------
// K1 (merged): blocks 0..159 do per-t aggregation; blocks 160.. do the
// in_proj -> bf16 WT transpose (independent work, saves one launch).
// ---------------------------------------------------------------------------
__global__ __launch_bounds__(256) void k1_agg(
    const float* __restrict__ input, const int* __restrict__ hem,
    const int* __restrict__ subnet, const float* __restrict__ hem_emb,
    const float* __restrict__ subnet_emb, float* __restrict__ gin,
    const float* __restrict__ ip, unsigned short* __restrict__ WT) {
  int tid = threadIdx.x;
  if (blockIdx.x >= 160) {
    int idx = (blockIdx.x - 160) * 256 + tid;
    if (idx < 96 * D_IN_PROJ) {
      int k = idx / D_IN_PROJ, n = idx - k * D_IN_PROJ;
      WT[(size_t)n * 96 + k] = bf16r(ip[idx]);
    }
    return;
  }
  int t = blockIdx.x;
  __shared__ float xs[96 * 96];
  __shared__ float al[96 * 48];
  __shared__ float s1[48];
  __shared__ float s2[96 * 48];

  for (int o = tid; o < 96 * 96; o += 256) {
    int i = o / 96, d = o % 96;
    xs[o] = input[i * TN + t * 96 + d];
  }
  for (int o = tid; o < 96 * 48; o += 256) {
    int i = o / 48, c = o % 48;
    al[o] = (c < 24) ? hem_emb[hem[i] * 24 + c]
                     : subnet_emb[subnet[i] * 24 + (c - 24)];
  }
  __syncthreads();
  if (tid < 48) {
    float s = 0.f;
    for (int i = 0; i < 96; i++) s += fmaxf(xs[i * 96 + tid] + al[i * 48 + tid], 0.f);
    s1[tid] = s;
  }
  for (int o = tid; o < 96 * 48; o += 256) {
    int j = o / 48, c = o % 48;
    float av = al[j * 48 + c];
    float s = 0.f;
    for (int i = 0; i < 96; i++) s += fmaxf(xs[i * 96 + 48 + c] + av, 0.f);
    s2[o] = s;
  }
  __syncthreads();
  for (int o = tid; o < 96 * 96; o += 256) {
    int j = o / 96, d = o % 96;
    float aggv = (d < 48) ? s1[d] : s2[j * 48 + (d - 48)];
    gin[t * 9216 + o] = xs[o] + aggv;
  }
}

// ---------------------------------------------------------------------------
// K2 (fused MLP + node-batchnorm), one block per t (96 rows = all nodes).
// ---------------------------------------------------------------------------
__global__ __launch_bounds__(256) void k2_fused(
    const float* __restrict__ gin, const float* __restrict__ input,
    const float* __restrict__ W1, const float* __restrict__ b1,
    const float* __restrict__ W2, const float* __restrict__ b2,
    const float* __restrict__ bn_w, const float* __restrict__ bn_b,
    float* __restrict__ z) {
  int t = blockIdx.x;
  __shared__ float As[96][100];
  __shared__ float Bs[96][96];
  __shared__ float mu[96], rs[96];
  int tid = threadIdx.x;
  int tx = tid & 15, ty = tid >> 4;
  int c0 = tx * 6;
  int r0 = ty * 6;

  for (int o = tid; o < 9216; o += 256) As[o / 96][o % 96] = gin[(size_t)t * 9216 + o];
  for (int o = tid; o < 9216; o += 256) Bs[o / 96][o % 96] = W1[o];
  __syncthreads();

  float acc[6][6];
#pragma unroll
  for (int i = 0; i < 6; i++)
#pragma unroll
    for (int j = 0; j < 6; j++) acc[i][j] = b1[c0 + j];

#pragma unroll 4
  for (int k = 0; k < 96; k++) {
    float a[6], bv[6];
#pragma unroll
    for (int i = 0; i < 6; i++) a[i] = As[r0 + i][k];
#pragma unroll
    for (int j = 0; j < 6; j++) bv[j] = Bs[k][c0 + j];
#pragma unroll
    for (int i = 0; i < 6; i++)
#pragma unroll
      for (int j = 0; j < 6; j++) acc[i][j] += a[i] * bv[j];
  }
  __syncthreads();

#pragma unroll
  for (int i = 0; i < 6; i++)
#pragma unroll
    for (int j = 0; j < 6; j++) As[r0 + i][c0 + j] = fmaxf(acc[i][j], 0.f);
  for (int o = tid; o < 9216; o += 256) Bs[o / 96][o % 96] = W2[o];
#pragma unroll
  for (int i = 0; i < 6; i++)
#pragma unroll
    for (int j = 0; j < 6; j++) acc[i][j] = b2[c0 + j];
  __syncthreads();

#pragma unroll 4
  for (int k = 0; k < 96; k++) {
    float a[6], bv[6];
#pragma unroll
    for (int i = 0; i < 6; i++) a[i] = As[r0 + i][k];
#pragma unroll
    for (int j = 0; j < 6; j++) bv[j] = Bs[k][c0 + j];
#pragma unroll
    for (int i = 0; i < 6; i++)
#pragma unroll
      for (int j = 0; j < 6; j++) acc[i][j] += a[i] * bv[j];
  }
#pragma unroll
  for (int i = 0; i < 6; i++) {
    const float* resr = input + (size_t)(r0 + i) * TN + t * 96 + c0;
#pragma unroll
    for (int j = 0; j < 6; j++) acc[i][j] += resr[j];
  }
  __syncthreads();
#pragma unroll
  for (int i = 0; i < 6; i++)
#pragma unroll
    for (int j = 0; j < 6; j++) As[r0 + i][c0 + j] = acc[i][j];
  __syncthreads();

  if (tid < 96) {
    float m = 0.f;
    for (int j = 0; j < 96; j++) m += As[j][tid];
    m *= (1.f / 96.f);
    float v = 0.f;
    for (int j = 0; j < 96; j++) { float dd = As[j][tid] - m; v += dd * dd; }
    v *= (1.f / 96.f);
    mu[tid] = m;
    rs[tid] = rsqrtf(v + BN_EPS);
  }
  __syncthreads();
  for (int o = tid; o < 9216; o += 256) {
    int j = o / 96, d = o % 96;
    z[(size_t)j * TN + t * 96 + d] = (As[j][d] - mu[d]) * rs[d] * bn_w[d] + bn_b[d];
  }
}

// ---------------------------------------------------------------------------
// K3: in_proj GEMM via bf16 MFMA -> bf16 zxw [15360][1160] + fp32 dtw [.][6].
// ---------------------------------------------------------------------------
__global__ __launch_bounds__(256) void k3_mfma(
    const float* __restrict__ Z, const unsigned short* __restrict__ WT,
    unsigned short* __restrict__ zxw, float* __restrict__ dtw) {
  int m0 = blockIdx.x * 128;
  int n0 = blockIdx.y * 64;
  __shared__ unsigned short As[128][104];
  __shared__ unsigned short Bs[64][104];
  unsigned short* Cs = &As[0][0];  // 128x64 staging (16KB), aliases As
  int tid = threadIdx.x;
  int lane = tid & 63, w = tid >> 6;

  for (int o = tid; o < 128 * 24; o += 256) {
    int r = o / 24, c4 = (o % 24) * 4;
    float4 v = *(const float4*)&Z[(size_t)(m0 + r) * 96 + c4];
    unsigned int p0 = pack_bf2(v.x, v.y);
    unsigned int p1 = pack_bf2(v.z, v.w);
    *(uint2*)&As[r][c4] = make_uint2(p0, p1);
  }
  for (int o = tid; o < 64 * 12; o += 256) {
    int nr = o / 12, seg = (o % 12) * 8;
    int n = n0 + nr;
    short8 v = {};
    if (n < D_IN_PROJ) v = *(const short8*)&WT[(size_t)n * 96 + seg];
    *(short8*)&Bs[nr][seg] = v;
  }
  __syncthreads();

  int q = lane >> 4, r16 = lane & 15;
  int wm = w * 32;
  f32x4 acc[2][4] = {};

#pragma unroll
  for (int ks = 0; ks < 3; ks++) {
    int k0 = ks * 32 + q * 8;
    short8 a0 = *(const short8*)&As[wm + r16][k0];
    short8 a1 = *(const short8*)&As[wm + 16 + r16][k0];
    short8 b0 = *(const short8*)&Bs[r16][k0];
    short8 b1 = *(const short8*)&Bs[16 + r16][k0];
    short8 b2 = *(const short8*)&Bs[32 + r16][k0];
    short8 b3 = *(const short8*)&Bs[48 + r16][k0];
    acc[0][0] = __builtin_amdgcn_mfma_f32_16x16x32_bf16(a0, b0, acc[0][0], 0, 0, 0);
    acc[0][1] = __builtin_amdgcn_mfma_f32_16x16x32_bf16(a0, b1, acc[0][1], 0, 0, 0);
    acc[0][2] = __builtin_amdgcn_mfma_f32_16x16x32_bf16(a0, b2, acc[0][2], 0, 0, 0);
    acc[0][3] = __builtin_amdgcn_mfma_f32_16x16x32_bf16(a0, b3, acc[0][3], 0, 0, 0);
    acc[1][0] = __builtin_amdgcn_mfma_f32_16x16x32_bf16(a1, b0, acc[1][0], 0, 0, 0);
    acc[1][1] = __builtin_amdgcn_mfma_f32_16x16x32_bf16(a1, b1, acc[1][1], 0, 0, 0);
    acc[1][2] = __builtin_amdgcn_mfma_f32_16x16x32_bf16(a1, b2, acc[1][2], 0, 0, 0);
    acc[1][3] = __builtin_amdgcn_mfma_f32_16x16x32_bf16(a1, b3, acc[1][3], 0, 0, 0);
  }

  __syncthreads();  // all As/Bs reads done before Cs (=As) overwrite

#pragma unroll
  for (int mf = 0; mf < 2; mf++) {
#pragma unroll
    for (int nf = 0; nf < 4; nf++) {
      int col = n0 + nf * 16 + r16;
      int rowb = wm + mf * 16 + q * 4;
#pragma unroll
      for (int reg = 0; reg < 4; reg++) {
        Cs[(rowb + reg) * 64 + nf * 16 + r16] = bf16r(acc[mf][nf][reg]);
        if (col >= 1152 && col < D_IN_PROJ)
          dtw[(size_t)(m0 + rowb + reg) * 6 + (col - 1152)] = acc[mf][nf][reg];
      }
    }
  }
  __syncthreads();

  for (int v = tid; v < 1024; v += 256) {
    int r = v >> 3, seg = (v & 7) * 8;
    if (n0 + seg + 8 <= ZXW_LD)
      *(short8*)&zxw[(size_t)(m0 + r) * ZXW_LD + n0 + seg] =
          *(const short8*)&Cs[r * 64 + seg];
  }
}

// ---------------------------------------------------------------------------
// K5 (fused conv + SSD): R14 structure with BATCHED conv loads (8 independent
// loads into a register buffer per batch -> deep VMEM pipelining, same
// thread=channel coalesced mapping). Everything else unchanged/verified.
// ---------------------------------------------------------------------------
__global__ __launch_bounds__(640) void k5_fused(
    const unsigned short* __restrict__ zxw, const float* __restrict__ dtw,
    const float* __restrict__ conv_w, const float* __restrict__ conv_b,
    const float* __restrict__ dt_bias, const float* __restrict__ A_log,
    const float* __restrict__ Dparam, float* __restrict__ y) {
  int b = blockIdx.x;  // 96
  int h = blockIdx.y;  // 6
  int tid = threadIdx.x;

  __shared__ __align__(16) unsigned char smem[67840];
  unsigned short* XdA = (unsigned short*)smem;            // 10240 B
  unsigned short* Bb = (unsigned short*)(smem + 10240);   // [160][72] 23040 B
  unsigned short* Cb = (unsigned short*)(smem + 33280);   // [160][72] 23040 B
  unsigned short* xb = (unsigned short*)(smem + 56320);   // [160][32] 10240 B
  float* dt_s = (float*)(smem + 66560);                   // [160]
  float* sc_a = (float*)(smem + 67200);                   // [160]

  float Ah = -expf(A_log[h]);
  float Dh = Dparam[h];
  float dtb = dt_bias[h];
  const unsigned short* zroww = zxw + (size_t)b * 160 * ZXW_LD;

  // ---- conv: thread = (channel cc, t-quarter tq); 40 rows each, batched ----
  {
    int cc = tid % 160, tq = tid / 160;
    int c, csrc;
    if (cc < 32) {
      c = h * 32 + cc;
      csrc = 192 + h * 32 + cc;
    } else if (cc < 96) {
      c = 192 + h * 64 + (cc - 32);
      csrc = 384 + h * 64 + (cc - 32);
    } else {
      c = 576 + h * 64 + (cc - 96);
      csrc = 768 + h * 64 + (cc - 96);
    }
    float cw0 = conv_w[c * 4 + 0], cw1 = conv_w[c * 4 + 1];
    float cw2 = conv_w[c * 4 + 2], cw3 = conv_w[c * 4 + 3];
    float cb = conv_b[c];
    unsigned short* cdst;
    int cstride;
    if (cc < 32)      { cdst = xb + cc;        cstride = 32; }
    else if (cc < 96) { cdst = Bb + (cc - 32); cstride = 72; }
    else              { cdst = Cb + (cc - 96); cstride = 72; }

    float rdt = 0.f;
    if (tid < 160) rdt = dtw[(size_t)(b * 160 + tid) * 6 + h];

    int t0 = tq * 40;
    float h0 = 0.f, h1 = 0.f, h2 = 0.f;
    if (tq > 0) {
      h0 = bf16f(zroww[(size_t)(t0 - 3) * ZXW_LD + csrc]);
      h1 = bf16f(zroww[(size_t)(t0 - 2) * ZXW_LD + csrc]);
      h2 = bf16f(zroww[(size_t)(t0 - 1) * ZXW_LD + csrc]);
    }
    // 5 batches of 8: independent loads fill dbuf (deep pipelining), then
    // the serial halo compute runs from registers.
#pragma unroll
    for (int gblk = 0; gblk < 5; gblk++) {
      int tb = t0 + gblk * 8;
      float dbuf[8];
#pragma unroll
      for (int i = 0; i < 8; i++)
        dbuf[i] = bf16f(zroww[(size_t)(tb + i) * ZXW_LD + csrc]);
#pragma unroll
      for (int i = 0; i < 8; i++) {
        float o = cb + h0 * cw0 + h1 * cw1 + h2 * cw2 + dbuf[i] * cw3;
        cdst[(tb + i) * cstride] = bf16r(siluf(o));
        h0 = h1; h1 = h2; h2 = dbuf[i];
      }
    }
    if (tid < 160) {
      float dtv = softplusf(rdt + dtb);
      dt_s[tid] = dtv;
      sc_a[tid] = dtv * Ah;
    }
  }
  __syncthreads();  // conv outputs + dt/log-decays visible

  // ---- waves 1-9: XdA fill, one contiguous 16B row per thread ----
  if (tid >= 64) {
    for (int row = tid - 64; row < 640; row += 576) {
      int p = row & 31, qq = (row >> 5) & 3, K = row >> 7;
      short8 v;
#pragma unroll
      for (int j = 0; j < 8; j++) {
        int tau = K * 32 + (j & 3) + 4 * qq + 16 * (j >> 2);
        ((unsigned short*)&v)[j] = bf16r(dt_s[tau] * bf16f(xb[tau * 32 + p]));
      }
      *(short8*)&XdA[row * 8] = v;
    }
  } else {
    // ---- wave 0: inclusive prefix scan of 160 log-decays via shfl ----
    int l = tid;
    float a = sc_a[l];
    float bseg = sc_a[64 + l];
    float cseg = (l < 32) ? sc_a[128 + l] : 0.f;
#pragma unroll
    for (int off = 1; off < 64; off <<= 1) {
      float u = __shfl_up(a, off);
      if (l >= off) a += u;
    }
    float s0 = __shfl(a, 63);
#pragma unroll
    for (int off = 1; off < 64; off <<= 1) {
      float u = __shfl_up(bseg, off);
      if (l >= off) bseg += u;
    }
    bseg += s0;
    float s1 = __shfl(bseg, 63);
#pragma unroll
    for (int off = 1; off < 32; off <<= 1) {
      float u = __shfl_up(cseg, off);
      if (l >= off) cseg += u;
    }
    cseg += s1;
    sc_a[l] = a;
    sc_a[64 + l] = bseg;
    if (l < 32) sc_a[128 + l] = cseg;
  }
  __syncthreads();  // XdA + scanned lc visible
  const float* lc = sc_a;

  // ---- MFMA phase: wave w owns t-tile [16w, 16w+16) ----
  int wid = tid >> 6, lane = tid & 63;
  int q = lane >> 4, r16 = lane & 15;
  int tbase = wid * 16;
  int t = tbase + r16;

  short8 cfr0 = *(const short8*)&Cb[t * 72 + q * 8];
  short8 cfr1 = *(const short8*)&Cb[t * 72 + 32 + q * 8];
  float lct = lc[t];
  f32x4 yacc[2] = {};
  int Kmax = wid >> 1;

  for (int K = 0; K <= Kmax; K++) {
    short8 bfr[2][2];
    f32x4 lc4[2];
#pragma unroll
    for (int i = 0; i < 2; i++) {
      int tr = (2 * K + i) * 16 + r16;
      bfr[i][0] = *(const short8*)&Bb[tr * 72 + q * 8];
      bfr[i][1] = *(const short8*)&Bb[tr * 72 + 32 + q * 8];
      lc4[i] = *(const f32x4*)&lc[(2 * K + i) * 16 + q * 4];
    }
    f32x4 g[2] = {};
#pragma unroll
    for (int i = 0; i < 2; i++) {
      g[i] = __builtin_amdgcn_mfma_f32_16x16x32_bf16(bfr[i][0], cfr0, g[i], 0, 0, 0);
      g[i] = __builtin_amdgcn_mfma_f32_16x16x32_bf16(bfr[i][1], cfr1, g[i], 0, 0, 0);
    }
#pragma unroll
    for (int i = 0; i < 2; i++) {
#pragma unroll
      for (int reg = 0; reg < 4; reg++) {
        int tau = 32 * K + i * 16 + q * 4 + reg;
        float w = (tau <= t) ? __expf(lct - lc4[i][reg]) : 0.f;
        g[i][reg] *= w;
      }
    }
    short8 xfr[2];
#pragma unroll
    for (int mf = 0; mf < 2; mf++)
      xfr[mf] = *(const short8*)&XdA[(((K * 4 + q) << 5) + mf * 16 + r16) * 8];
    union { short8 s; unsigned int u[4]; } sb;
    sb.u[0] = pack_bf2(g[0][0], g[0][1]);
    sb.u[1] = pack_bf2(g[0][2], g[0][3]);
    sb.u[2] = pack_bf2(g[1][0], g[1][1]);
    sb.u[3] = pack_bf2(g[1][2], g[1][3]);
#pragma unroll
    for (int mf = 0; mf < 2; mf++)
      yacc[mf] = __builtin_amdgcn_mfma_f32_16x16x32_bf16(xfr[mf], sb.s, yacc[mf], 0, 0, 0);
  }

  // ---- epilogue: y = yacc + D*x ----
#pragma unroll
  for (int mf = 0; mf < 2; mf++) {
    int p0 = mf * 16 + q * 4;
    float4 o;
    float* op = (float*)&o;
#pragma unroll
    for (int reg = 0; reg < 4; reg++) {
      float xv = bf16f(xb[t * 32 + p0 + reg]);
      op[reg] = yacc[mf][reg] + Dh * xv;
    }
    *(float4*)&y[((size_t)(b * 160 + t)) * D_INNER + h * 32 + p0] = o;
  }
}

// ---------------------------------------------------------------------------
// K6 v3: gated RMSNorm + out_proj + partial time-mean (R19-verified).
// ---------------------------------------------------------------------------
#define K6T 16
#define K6LD 204

__global__ __launch_bounds__(256) void k6_head(
    const float* __restrict__ y, const unsigned short* __restrict__ zxw,
    const float* __restrict__ norm_w, const float* __restrict__ out_proj,
    float* __restrict__ e_part) {
  int b = blockIdx.x;
  int ch = blockIdx.y;  // 10 chunks x 16 timesteps
  int tid = threadIdx.x;
  __shared__ float g[K6T][K6LD];
  __shared__ float rf[K6T];
  __shared__ float nw[192];
  __shared__ float ep[K6T][97];
  __shared__ unsigned short opj[192 * 96];  // bf16 out_proj, 36864 B
  int t0 = ch * K6T;

  if (tid < 192) nw[tid] = norm_w[tid];

  for (int o = tid; o < 4608; o += 256) {
    float4 v = *(const float4*)&out_proj[o * 4];
    unsigned int p0 = pack_bf2(v.x, v.y);
    unsigned int p1 = pack_bf2(v.z, v.w);
    *(uint2*)&opj[o * 4] = make_uint2(p0, p1);
  }

  for (int v = tid; v < K6T * 24; v += 256) {
    int tt = v / 24, c8 = (v % 24) * 8;
    size_t row = (size_t)(b * 160 + t0 + tt);
    short8 zg8 = *(const short8*)&zxw[row * ZXW_LD + c8];
    float4 y0 = *(const float4*)&y[row * D_INNER + c8];
    float4 y1 = *(const float4*)&y[row * D_INNER + c8 + 4];
    float* yp0 = (float*)&y0;
    float* yp1 = (float*)&y1;
    float4 g0, g1;
    float* gp0 = (float*)&g0;
    float* gp1 = (float*)&g1;
#pragma unroll
    for (int k = 0; k < 4; k++)
      gp0[k] = yp0[k] * siluf(bf16f((unsigned short)zg8[k]));
#pragma unroll
    for (int k = 0; k < 4; k++)
      gp1[k] = yp1[k] * siluf(bf16f((unsigned short)zg8[4 + k]));
    *(float4*)&g[tt][c8] = g0;
    *(float4*)&g[tt][c8 + 4] = g1;
  }
  __syncthreads();

  {
    int tt = tid >> 4, l = tid & 15;
    float ss = 0.f;
    for (int k = l; k < 192; k += 16) {
      float v = g[tt][k];
      ss += v * v;
    }
    ss += __shfl_xor(ss, 1);
    ss += __shfl_xor(ss, 2);
    ss += __shfl_xor(ss, 4);
    ss += __shfl_xor(ss, 8);
    if (l == 0) rf[tt] = rsqrtf(ss * (1.f / 192.f) + RMS_EPS);
  }
  __syncthreads();

  if (tid < 192) {
    int tt = tid & 15, grp = tid >> 4;
    int d0 = grp * 8;
    float rr = rf[tt];
    float acc[8] = {};
    for (int k = 0; k < 192; k += 4) {
      float4 g4 = *(const float4*)&g[tt][k];
      float4 n4 = *(const float4*)&nw[k];
      const float* gp = (const float*)&g4;
      const float* np = (const float*)&n4;
#pragma unroll
      for (int kk = 0; kk < 4; kk++) {
        float gk = gp[kk] * rr * np[kk];
        short8 w8 = *(const short8*)&opj[(k + kk) * 96 + d0];
#pragma unroll
        for (int j = 0; j < 8; j++)
          acc[j] += gk * bf16f((unsigned short)w8[j]);
      }
    }
#pragma unroll
    for (int j = 0; j < 8; j++) ep[tt][d0 + j] = acc[j];
  }
  __syncthreads();

  if (tid < 96) {
    float sum = 0.f;
#pragma unroll
    for (int tt = 0; tt < K6T; tt++) sum += ep[tt][tid];
    e_part[(size_t)ch * 9216 + b * 96 + tid] = sum;
  }
}

// ---------------------------------------------------------------------------
// K7: reduce chunks, final heads: x1, mu, sigma
// ---------------------------------------------------------------------------
__global__ __launch_bounds__(128) void k7_out(
    const float* __restrict__ e_part, const float* __restrict__ fcw,
    const float* __restrict__ fcb, const float* __restrict__ mu_w,
    const float* __restrict__ mu_b, const float* __restrict__ sg_w,
    const float* __restrict__ sg_b, float* __restrict__ out) {
  int b = blockIdx.x;
  int tid = threadIdx.x;
  __shared__ float em[96];
  __shared__ float x1[96];
  if (tid < 96) {
    float s = 0.f;
    for (int c = 0; c < 10; c++) s += e_part[(size_t)c * 9216 + b * 96 + tid];
    em[tid] = s * (1.f / 160.f);
  }
  __syncthreads();
  if (tid < 96) {
    float acc = fcb[tid];
    for (int k = 0; k < 96; k++) acc += em[k] * fcw[k * 96 + tid];
    float tv = tanhf(acc);
    float ev = (tv > 0.f) ? tv : expm1f(tv);
    x1[tid] = ev;
    out[b * 96 + tid] = ev;
  }
  __syncthreads();
  int j = tid & 63, which = tid >> 6;
  if (which == 0) {
    float acc = mu_b[j];
    for (int k = 0; k < 96; k++) acc += x1[k] * mu_w[k * 64 + j];
    out[9216 + b * 64 + j] = acc;
  } else {
    float acc = sg_b[j];
    for (int k = 0; k < 96; k++) acc += x1[k] * sg_w[k * 64 + j];
    float ev = (acc > 0.f) ? acc : expm1f(acc);
    out[9216 + 6144 + b * 64 + j] = ev + 1.f + 1e-14f;
  }
}

// ---------------------------------------------------------------------------
extern "C" void kernel_launch(void* const* d_in, const int* in_sizes, int n_in,
                              void* d_out, int out_size, void* d_ws,
                              size_t ws_size, hipStream_t stream) {
  const float* input      = (const float*)d_in[0];
  const int*   hem        = (const int*)d_in[1];
  const int*   subnet     = (const int*)d_in[2];
  const float* gine_w1    = (const float*)d_in[3];
  const float* gine_b1    = (const float*)d_in[4];
  const float* gine_w2    = (const float*)d_in[5];
  const float* gine_b2    = (const float*)d_in[6];
  const float* bn_w       = (const float*)d_in[7];
  const float* bn_b       = (const float*)d_in[8];
  const float* hem_emb    = (const float*)d_in[9];
  const float* subnet_emb = (const float*)d_in[10];
  const float* in_proj    = (const float*)d_in[11];
  const float* conv_w     = (const float*)d_in[12];
  const float* conv_b     = (const float*)d_in[13];
  const float* dt_bias    = (const float*)d_in[14];
  const float* A_log      = (const float*)d_in[15];
  const float* Dparam     = (const float*)d_in[16];
  const float* norm_w     = (const float*)d_in[17];
  const float* out_proj   = (const float*)d_in[18];
  const float* out_fc_w   = (const float*)d_in[19];
  const float* out_fc_b   = (const float*)d_in[20];
  const float* mu_w       = (const float*)d_in[21];
  const float* mu_b       = (const float*)d_in[22];
  const float* sigma_w    = (const float*)d_in[23];
  const float* sigma_b    = (const float*)d_in[24];

  float* ws = (float*)d_ws;
  float* gin    = ws;                  // 1,474,560
  float* z      = gin + 1474560;       // 1,474,560
  float* zxf    = z + 1474560;         // 17,786,880 fp32 slots -> holds bf16 zxw
  float* y      = zxf + 17786880;      // 2,949,120
  float* e_part = y + 2949120;         // 92,160 (10 chunks)
  float* dtw    = e_part + 92160;      // 92,160 (15360 x 6 fp32 dt)
  unsigned short* zxw = (unsigned short*)zxf;  // [15360][1160] bf16
  // WT (bf16 in_proj^T) aliases the TAIL of y: k1(WT) -> k3 -> k5 (overwrites y)
  unsigned short* WT = (unsigned short*)(y + 2893536);
  float* outp = (float*)d_out;

  k1_agg<<<595, 256, 0, stream>>>(input, hem, subnet, hem_emb, subnet_emb,
                                  gin, in_proj, WT);
  k2_fused<<<160, 256, 0, stream>>>(gin, input, gine_w1, gine_b1, gine_w2,
                                    gine_b2, bn_w, bn_b, z);
  k3_mfma<<<dim3(120, 19), 256, 0, stream>>>(z, WT, zxw, dtw);
  k5_fused<<<dim3(96, 6), 640, 0, stream>>>(zxw, dtw, conv_w, conv_b, dt_bias,
                                            A_log, Dparam, y);
  k6_head<<<dim3(96, 10), 256, 0, stream>>>(y, zxw, norm_w, out_proj, e_part);
  k7_out<<<96, 128, 0, stream>>>(e_part, out_fc_w, out_fc_b, mu_w, mu_b,
                                 sigma_w, sigma_b, outp);
}